// Round 15
// baseline (122.282 us; speedup 1.0000x reference)
//
#include <hip/hip_runtime.h>
#include <math.h>

#define BOS_TAG 62
#define EOS_TAG 63
#define S_LEN   1024
#define NCH     64
#define CH      16          // S_LEN / NCH
#define WPB     4           // NCH/16 fwd waves per batch (same for bwd)
#define LN2F    0.69314718055994530942f

typedef short  short8 __attribute__((ext_vector_type(8)));
typedef float  f32x4  __attribute__((ext_vector_type(4)));

template <int CTRL>
__device__ __forceinline__ int dpp_mov(int v) {
  return __builtin_amdgcn_update_dpp(v, v, CTRL, 0xf, 0xf, false);
}
template <int CTRL>
__device__ __forceinline__ float dpp_fmax_step(float v) {
  return fmaxf(v, __int_as_float(dpp_mov<CTRL>(__float_as_int(v))));
}
__device__ __forceinline__ float wave_fmax_all(float v) {
  v = dpp_fmax_step<0x111>(v); v = dpp_fmax_step<0x112>(v);
  v = dpp_fmax_step<0x114>(v); v = dpp_fmax_step<0x118>(v);
  v = dpp_fmax_step<0x142>(v); v = dpp_fmax_step<0x143>(v);
  return __int_as_float(__builtin_amdgcn_readlane(__float_as_int(v), 63));
}
template <int CTRL>
__device__ __forceinline__ float dpp_fadd_step(float v) {
  int t = __builtin_amdgcn_update_dpp(0, __float_as_int(v), CTRL, 0xf, 0xf, true);
  return v + __int_as_float(t);
}
__device__ __forceinline__ float wave_sum_all(float v) {
  v = dpp_fadd_step<0x111>(v); v = dpp_fadd_step<0x112>(v);
  v = dpp_fadd_step<0x114>(v); v = dpp_fadd_step<0x118>(v);
  v = dpp_fadd_step<0x142>(v); v = dpp_fadd_step<0x143>(v);
  return __int_as_float(__builtin_amdgcn_readlane(__float_as_int(v), 63));
}
__device__ __forceinline__ unsigned short f2bf(float v) {   // round-half-up (positive)
  return (unsigned short)((__float_as_uint(v) + 0x8000u) >> 16);
}
// schedulable packed pair (NO inline asm: asm fences hurt scheduling, R12)
__device__ __forceinline__ unsigned pk2(float lo, float hi) {
  return ((__float_as_uint(lo) + 0x8000u) >> 16)
       | (((__float_as_uint(hi) + 0x8000u) >> 16) << 16);
}
__device__ __forceinline__ float bf2f(unsigned short u) {
  return __uint_as_float(((unsigned)u) << 16);
}

// ===== lens: len[b] = round(sum(mask[b,:])) =====
__global__ __launch_bounds__(256) void crf_lens(
    const float* __restrict__ mask, int* __restrict__ lens, int B)
{
  const int b = blockIdx.x * 4 + (threadIdx.x >> 6);
  if (b >= B) return;
  const int l = threadIdx.x & 63;
  const float4* mb = (const float4*)(mask + (size_t)b * S_LEN);
  float s = 0.f;
#pragma unroll
  for (int i = 0; i < 4; ++i) { float4 q = mb[l + 64 * i]; s += q.x + q.y + q.z + q.w; }
  s = wave_sum_all(s);
  if (l == 0) lens[b] = max(1, min(S_LEN, (int)(s + 0.5f)));
}

// ===== ptab: per-lane MFMA B-fragment table + exp(trans[:,EOS]) =====
__global__ __launch_bounds__(256) void crf_ptab(
    const float* __restrict__ trans, short8* __restrict__ pfrag,
    float* __restrict__ tvf)
{
  const int tid = threadIdx.x;
  for (int e = tid; e < 1024; e += 256) {
    int lane = e & 63, n = (e >> 6) & 3, kc = (e >> 8) & 1, dir = e >> 9;
    int g = lane >> 4, c = lane & 15, col = 4 * c + n;
    short8 f;
#pragma unroll
    for (int j = 0; j < 8; ++j) {
      int k = kc * 32 + g * 8 + j;
      float tv = dir ? trans[col * 64 + k] : trans[k * 64 + col];
      f[j] = (short)f2bf(__expf(tv));
    }
    pfrag[e] = f;
  }
  if (tid < 64) tvf[tid] = __expf(trans[tid * 64 + EOS_TAG]);
}

// ===== MFMA chunk kernel =====
// wave w: dir=w&1, idx=w>>1, b=idx/WPB, half=idx%WPB. Row r <-> chunk
// kg=half*16+r. State tiling: tile n, lane-col c <-> state 4c+n. A k-slot
// (kc,g,j) <-> state 32kc+8g+j. LDS bf16 word (row*64+state) ^ swizzle.
// fwd: V <- (V x P) .* E_t ; saves from LDS.
// bwd (w-state): w(tend)=E_tend; 15x w <- E_t .* (P^T x w); epilogue
// u(tstart) = P^T x w saved directly from MFMA accumulators.
// NOTES: (256,3) = proven no-spill launch bound (84 VGPR); (256,4) spilled
// (R11). NO per-thread arrays with ANY runtime-indexed access: fstep[l]
// (R13) and fstep[4*g+reg] (R14) each kept fstep[16] in scratch -> +62MB
// writes, 120us chunks. fstep is now ELIMINATED; all row predicates are
// recomputed arithmetically from (half, r, len).
__global__ __launch_bounds__(256, 3) void crf_chunk_mfma(
    const float* __restrict__ em, const float* __restrict__ trans,
    const int* __restrict__ lens, const short8* __restrict__ pfrag,
    unsigned short* __restrict__ Vf, unsigned short* __restrict__ Vb,
    float* __restrict__ sf, float* __restrict__ sb,
    float* __restrict__ m0a, int B)
{
  __shared__ unsigned short smem[4][16 * 64];
  const int wv = threadIdx.x >> 6;
  const int l  = threadIdx.x & 63;
  const int w  = blockIdx.x * 4 + wv;
  const int nwaves = 2 * B * WPB;
  if (w >= nwaves) return;
  const int dir  = w & 1;
  const int idx  = w >> 1;
  const int b    = idx / WPB;
  const int half = idx % WPB;
  unsigned short* smw = smem[wv];
  const float* embase = em + (size_t)b * S_LEN * 64;
  const int g = l >> 4, c = l & 15;

  const int len = lens[b];

  // row predicates (pure arithmetic; NO arrays):
  //   empty(r):  half*16+r)*CH + 1 > len-1
  //   full(r):   (half*16+r+1)*CH <= len-1
  //   fstep(r) = min((kg+1)*CH, len-1) - (kg*CH+1)

  // ---- alpha0 (fwd half==0 only) ----
  float v_row0 = 1.0f;
  if (dir == 0 && half == 0) {
    float a0 = trans[BOS_TAG * 64 + l] + embase[l];
    float m0 = wave_fmax_all(a0);
    v_row0 = __expf(a0 - m0);
    if (l == 0) m0a[b] = m0;
  }

  // ---- pre-save empty rows; find the partial row (ps,pr scalars) ----
  unsigned short* Vout = dir ? Vb : Vf;
  float* sout = dir ? sb : sf;
  int ps = -1, pr = -1;
#pragma unroll
  for (int r = 0; r < 16; ++r) {
    int kg = half * 16 + r;
    int fs = min((kg + 1) * CH, len - 1) - (kg * CH + 1);
    if (fs < 0) {
      Vout[((size_t)b * NCH + kg) * 64 + l] = 0x3F80; // bf16 1.0
      if (l == 0) sout[b * NCH + kg] = 0.f;
    }
    if (fs >= 0 && fs < CH - 1) { ps = fs; pr = r; }
  }

  if (half * 16 * CH + 1 > len - 1) return; // fully-empty wave

  // ---- B fragments: 8 coalesced 16B loads from pfrag ----
  short8 Bf[2][4];
  {
    const short8* pf = pfrag + dir * 512;
#pragma unroll
    for (int kc = 0; kc < 2; ++kc)
#pragma unroll
      for (int n = 0; n < 4; ++n)
        Bf[kc][n] = pf[(kc * 4 + n) * 64 + l];
  }

  const int byteA0 = (c * 128 + g * 16) ^ ((c & 7) << 4);
  const int byteA1 = (c * 128 + 64 + g * 16) ^ ((c & 7) << 4);
  int sigma = 0;

  auto renorm16 = [&](float* d) {
    float m = d[0];
#pragma unroll
    for (int i = 1; i < 16; ++i) m = fmaxf(m, d[i]);
    m = wave_fmax_all(m);
    int e = ((__float_as_int(m) >> 23) & 0xff) - 127;
    float s = __int_as_float((127 - e) << 23);
#pragma unroll
    for (int i = 0; i < 16; ++i) d[i] *= s;
    sigma += e;
  };
  auto mfma8 = [&](f32x4* acc) {
    short8 a0 = *reinterpret_cast<const short8*>((const char*)smw + byteA0);
    short8 a1 = *reinterpret_cast<const short8*>((const char*)smw + byteA1);
#pragma unroll
    for (int n = 0; n < 4; ++n) {
      f32x4 z = {0.f, 0.f, 0.f, 0.f};
      z = __builtin_amdgcn_mfma_f32_16x16x32_bf16(a0, Bf[0][n], z, 0, 0, 0);
      acc[n] = __builtin_amdgcn_mfma_f32_16x16x32_bf16(a1, Bf[1][n], z, 0, 0, 0);
    }
  };
  auto write_d = [&](const float* d) {
#pragma unroll
    for (int reg = 0; reg < 4; ++reg) {
      int row = g * 4 + reg;
      uint2 wq;
      wq.x = pk2(d[reg * 4 + 0], d[reg * 4 + 1]);
      wq.y = pk2(d[reg * 4 + 2], d[reg * 4 + 3]);
      *reinterpret_cast<uint2*>(
          (char*)smw + ((row * 128 + c * 8) ^ ((row & 7) << 4))) = wq;
    }
  };
  auto save_row_lds = [&](int r) {   // fwd: save row r from LDS
    unsigned short v = smw[(r * 64 + l) ^ ((r & 7) << 3)];
    int kg = half * 16 + r;
    Vout[((size_t)b * NCH + kg) * 64 + l] = v;
    if (l == 0) sout[b * NCH + kg] = (float)sigma;
  };

  int tb0[4];
#pragma unroll
  for (int reg = 0; reg < 4; ++reg) {
    int kg = half * 16 + g * 4 + reg;
    tb0[reg] = dir ? (min((kg + 1) * CH, len - 1) - 1) : (kg * CH + 1);
  }
  auto loadE = [&](float4* q, int tl) {
#pragma unroll
    for (int reg = 0; reg < 4; ++reg) {
      int tr = dir ? max(tb0[reg] - tl, 0) : min(tb0[reg] + tl, S_LEN - 1);
      q[reg] = *reinterpret_cast<const float4*>(embase + (size_t)tr * 64 + 4 * c);
    }
  };

  if (dir == 0) {
    auto bodyF = [&](const float4* q, int tl, bool rn) {
      f32x4 acc[4];
      mfma8(acc);
      float d[16];
#pragma unroll
      for (int reg = 0; reg < 4; ++reg) {
        d[reg * 4 + 0] = acc[0][reg] * __expf(q[reg].x);
        d[reg * 4 + 1] = acc[1][reg] * __expf(q[reg].y);
        d[reg * 4 + 2] = acc[2][reg] * __expf(q[reg].z);
        d[reg * 4 + 3] = acc[3][reg] * __expf(q[reg].w);
      }
      if (rn) renorm16(d);
      write_d(d);
      if (tl == ps) save_row_lds(pr);
    };

    // init V rows
#pragma unroll
    for (int r = 0; r < 16; ++r) {
      float v = (half == 0 && r == 0) ? v_row0 : 1.0f;
      smw[(r * 64 + l) ^ ((r & 7) << 3)] = f2bf(v);
    }

    float4 p0[4], p1[4], p2[4], p3[4];
    loadE(p0, 0); loadE(p1, 1); loadE(p2, 2); loadE(p3, 3);
#pragma unroll 1
    for (int t4 = 0; t4 < CH; t4 += 4) {
      bodyF(p0, t4 + 0, false); loadE(p0, t4 + 4);
      bodyF(p1, t4 + 1, false); loadE(p1, t4 + 5);
      bodyF(p2, t4 + 2, false); loadE(p2, t4 + 6);
      bodyF(p3, t4 + 3, true);  loadE(p3, t4 + 7);
    }
#pragma unroll
    for (int r = 0; r < 16; ++r)
      if ((half * 16 + r + 1) * CH <= len - 1) save_row_lds(r);
  } else {
    // epilogue: u = P^T x w from accumulators; save rows directly.
    // full-row predicate recomputed arithmetically (runtime r is fine:
    // it's register math, not an array index).
    auto epi_save = [&](bool finalAll) {
      f32x4 acc[4];
      mfma8(acc);
#pragma unroll
      for (int reg = 0; reg < 4; ++reg) {
        int r = 4 * g + reg;
        bool full = (half * 16 + r + 1) * CH <= len - 1;
        bool doit = finalAll ? full : (r == pr);
        if (doit) {
          uint2 val;
          val.x = pk2(acc[0][reg], acc[1][reg]);
          val.y = pk2(acc[2][reg], acc[3][reg]);
          *reinterpret_cast<uint2*>(
              Vout + ((size_t)b * NCH + half * 16 + r) * 64 + 4 * c) = val;
        }
      }
      if (finalAll) {
        if (l < 16 && (half * 16 + l + 1) * CH <= len - 1)
          sout[b * NCH + half * 16 + l] = (float)sigma;
      } else if (l == 0) {
        sout[b * NCH + half * 16 + pr] = (float)sigma;
      }
    };
    auto bodyB = [&](const float4* q, int tl, bool rn) {
      f32x4 acc[4];
      mfma8(acc);
      float d[16];
#pragma unroll
      for (int reg = 0; reg < 4; ++reg) {
        d[reg * 4 + 0] = acc[0][reg] * __expf(q[reg].x);
        d[reg * 4 + 1] = acc[1][reg] * __expf(q[reg].y);
        d[reg * 4 + 2] = acc[2][reg] * __expf(q[reg].z);
        d[reg * 4 + 3] = acc[3][reg] * __expf(q[reg].w);
      }
      if (rn) renorm16(d);
      write_d(d);
      if (tl == ps - 1) epi_save(false);
    };

    // init w rows: exp(E at tend_r) for active rows, 1.0 for empty
#pragma unroll
    for (int r = 0; r < 16; ++r) {
      int kg = half * 16 + r;
      int tendr = min((kg + 1) * CH, len - 1);
      bool active = (kg * CH + 1 <= len - 1);
      float v = active ? __expf(embase[(size_t)tendr * 64 + l]) : 1.0f;
      smw[(r * 64 + l) ^ ((r & 7) << 3)] = f2bf(v);
    }
    if (ps == 0) epi_save(false); // 1-step partial row

    float4 p0[4], p1[4], p2[4], p3[4];
    loadE(p0, 0); loadE(p1, 1); loadE(p2, 2); loadE(p3, 3);
#pragma unroll 1
    for (int t4 = 0; t4 < 12; t4 += 4) {
      bodyB(p0, t4 + 0, false); loadE(p0, t4 + 4);
      bodyB(p1, t4 + 1, false); loadE(p1, t4 + 5);
      bodyB(p2, t4 + 2, false); loadE(p2, t4 + 6);
      bodyB(p3, t4 + 3, true);  loadE(p3, t4 + 7);
    }
    bodyB(p0, 12, false); bodyB(p1, 13, false); bodyB(p2, 14, false);
    epi_save(true);
  }
}

// ===== combine: one wave per (b,k) term; includes gold-score slice =====
__global__ __launch_bounds__(256) void crf_combine(
    const float* __restrict__ em, const int* __restrict__ tags,
    const float* __restrict__ trans, const int* __restrict__ lens,
    const unsigned short* __restrict__ Vf, const unsigned short* __restrict__ Vb,
    const float* __restrict__ sf, const float* __restrict__ sb,
    const float* __restrict__ m0a, const float* __restrict__ tvf,
    float* __restrict__ term, int B)
{
  const int item = blockIdx.x * 4 + (threadIdx.x >> 6);
  if (item >= B * NCH) return;
  const int b = item / NCH, k = item - b * NCH;
  const int l = threadIdx.x & 63;
  const int len = lens[b];
  const int kb = (len >= 2) ? (len - 2) / CH : 0;

  const int* tb = tags + (size_t)b * S_LEN;
  const float* emb = em + (size_t)b * S_LEN * 64;

  float t = 0.f;
  {
    float sc = 0.f;
    int t0 = k * CH + 1 + l;
    if (l < CH && t0 <= len - 1) {
      int cur = tb[t0], prev = tb[t0 - 1];
      sc = emb[(size_t)t0 * 64 + cur] + trans[prev * 64 + cur];
    }
    if (k == 0) {
      if (l == 32) sc += trans[BOS_TAG * 64 + tb[0]] + emb[tb[0]];
      if (l == 33) sc += trans[tb[len - 1] * 64 + EOS_TAG];
    }
    t -= wave_sum_all(sc);
  }

  const unsigned short* vf = Vf + ((size_t)b * NCH + k) * 64;
  if (k == 0) {
    float v0 = bf2f(vf[l]);
    if (kb == 0) {
      t += m0a[b] + LN2F * sf[b * NCH] + __logf(wave_sum_all(v0 * tvf[l]));
    } else {
      t += m0a[b] + LN2F * (sf[b * NCH] + sb[b * NCH + 1])
         + __logf(wave_sum_all(v0 * bf2f(Vb[((size_t)b * NCH + 1) * 64 + l])));
    }
  } else if (k < kb) {
    float vk = bf2f(vf[l]);
    t += LN2F * sb[b * NCH + k + 1]
       + __logf(wave_sum_all(vk * bf2f(Vb[((size_t)b * NCH + k + 1) * 64 + l])))
       - __logf(wave_sum_all(vk));
  } else if (k == kb) {
    float vk = bf2f(vf[l]);
    t += __logf(wave_sum_all(vk * tvf[l])) - __logf(wave_sum_all(vk));
  }

  if (l == 0) term[item] = t;
}

// ===== final: sum all terms -> out[0] =====
__global__ __launch_bounds__(1024) void crf_final(
    const float* __restrict__ term, float* __restrict__ out, int n)
{
  __shared__ float red[16];
  float s = 0.f;
  for (int i = threadIdx.x; i < n; i += 1024) s += term[i];
  s = wave_sum_all(s);
  const int wid = threadIdx.x >> 6;
  if ((threadIdx.x & 63) == 0) red[wid] = s;
  __syncthreads();
  if (threadIdx.x == 0) {
    float tot = 0.f;
#pragma unroll
    for (int i = 0; i < 16; ++i) tot += red[i];
    out[0] = tot;
  }
}

// ===== fallback: monolithic per-batch forward (VALU, linear space) =====
__global__ __launch_bounds__(64) void crf_mono(
    const float* __restrict__ em, const int* __restrict__ tags,
    const float* __restrict__ mask, const float* __restrict__ trans,
    float* __restrict__ partial)
{
  const int b = blockIdx.x;
  const int l = threadIdx.x;
  const float* emb = em + (size_t)b * S_LEN * 64;
  const float* mb = mask + (size_t)b * S_LEN;
  float lenf = 0.f;
  for (int t = l; t < S_LEN; t += 64) lenf += mb[t];
  lenf = wave_sum_all(lenf);
  const int len = max(1, min(S_LEN, (int)(lenf + 0.5f)));

  float p[64];
#pragma unroll
  for (int i = 0; i < 64; ++i) p[i] = __expf(trans[i * 64 + l]) * 0.015625f;

  const int* tb = tags + (size_t)b * S_LEN;
  float sc = 0.f;
  for (int tt = 1 + l; tt <= len - 1; tt += 64)
    sc += emb[(size_t)tt * 64 + tb[tt]] + trans[tb[tt - 1] * 64 + tb[tt]];
  sc = wave_sum_all(sc);
  sc += trans[BOS_TAG * 64 + tb[0]] + emb[tb[0]] + trans[tb[len - 1] * 64 + EOS_TAG];

  float a0 = trans[BOS_TAG * 64 + l] + emb[l];
  float m0 = wave_fmax_all(a0);
  float v = __expf(a0 - m0);
  int sigma = 0;
  for (int t = 1; t <= len - 1; ++t) {
    float E = __expf(emb[(size_t)t * 64 + l]);
    int xi = __float_as_int(v);
    float s0 = 0.f, s1 = 0.f, s2 = 0.f, s3 = 0.f;
#pragma unroll
    for (int i = 0; i < 64; i += 4) {
      s0 = fmaf(__int_as_float(__builtin_amdgcn_readlane(xi, i + 0)), p[i + 0], s0);
      s1 = fmaf(__int_as_float(__builtin_amdgcn_readlane(xi, i + 1)), p[i + 1], s1);
      s2 = fmaf(__int_as_float(__builtin_amdgcn_readlane(xi, i + 2)), p[i + 2], s2);
      s3 = fmaf(__int_as_float(__builtin_amdgcn_readlane(xi, i + 3)), p[i + 3], s3);
    }
    v = ((s0 + s1) + (s2 + s3)) * E;
    float m = wave_fmax_all(v);
    int e = ((__float_as_int(m) >> 23) & 0xff) - 127;
    sigma += e + 6;
    v *= __int_as_float((127 - e) << 23);
  }
  float tvec = __expf(trans[l * 64 + EOS_TAG]);
  float lp = m0 + LN2F * (float)sigma + __logf(wave_sum_all(v * tvec));
  if (l == 0) partial[b] = lp - sc;
}

extern "C" void kernel_launch(void* const* d_in, const int* in_sizes, int n_in,
                              void* d_out, int out_size, void* d_ws, size_t ws_size,
                              hipStream_t stream) {
  const float* em = (const float*)d_in[0];
  const int* tags = (const int*)d_in[1];
  const float* mask = (const float*)d_in[2];
  const float* trans = (const float*)d_in[3];
  float* out = (float*)d_out;

  const int B = in_sizes[1] / S_LEN;

  const size_t nSig = (size_t)B * NCH;
  const size_t nV   = (size_t)B * NCH * 64;
  const size_t need = 16384 + 64 * sizeof(float)
                    + (3 * nSig + (size_t)B) * sizeof(float)
                    + (size_t)B * sizeof(int)
                    + 2 * nV * sizeof(unsigned short);

  if (ws_size >= need) {
    short8* pfrag = (short8*)d_ws;
    float* tvf  = (float*)((char*)d_ws + 16384);
    float* sf   = tvf + 64;
    float* sb   = sf + nSig;
    float* m0a  = sb + nSig;
    float* term = m0a + B;
    int*   lens = (int*)(term + nSig);
    unsigned short* Vf = (unsigned short*)(lens + B);
    unsigned short* Vb = Vf + nV;

    crf_lens<<<(B + 3) / 4, 256, 0, stream>>>(mask, lens, B);
    crf_ptab<<<1, 256, 0, stream>>>(trans, pfrag, tvf);
    const int nwaves = 2 * B * WPB;
    crf_chunk_mfma<<<(nwaves + 3) / 4, 256, 0, stream>>>(
        em, trans, lens, pfrag, Vf, Vb, sf, sb, m0a, B);
    crf_combine<<<(B * NCH + 3) / 4, 256, 0, stream>>>(
        em, tags, trans, lens, Vf, Vb, sf, sb, m0a, tvf, term, B);
    crf_final<<<1, 1024, 0, stream>>>(term, out, B * NCH);
  } else {
    float* partial = (float*)d_ws;
    crf_mono<<<B, 64, 0, stream>>>(em, tags, mask, trans, partial);
    crf_final<<<1, 1024, 0, stream>>>(partial, out, B);
  }
}

// Round 16
// 73.727 us; speedup vs baseline: 1.6586x; 1.6586x over previous
//
#include <hip/hip_runtime.h>
#include <math.h>

#define BOS_TAG 62
#define EOS_TAG 63
#define S_LEN   1024
#define NCH     32
#define CH      32          // S_LEN / NCH
#define WPB     2           // NCH/16 fwd waves per batch (same for bwd)
#define LN2F    0.69314718055994530942f

typedef short  short8 __attribute__((ext_vector_type(8)));
typedef unsigned short ushort4v __attribute__((ext_vector_type(4)));
typedef float  f32x4  __attribute__((ext_vector_type(4)));

template <int CTRL>
__device__ __forceinline__ int dpp_mov(int v) {
  return __builtin_amdgcn_update_dpp(v, v, CTRL, 0xf, 0xf, false);
}
template <int CTRL>
__device__ __forceinline__ float dpp_fmax_step(float v) {
  return fmaxf(v, __int_as_float(dpp_mov<CTRL>(__float_as_int(v))));
}
__device__ __forceinline__ float wave_fmax_all(float v) {
  v = dpp_fmax_step<0x111>(v); v = dpp_fmax_step<0x112>(v);
  v = dpp_fmax_step<0x114>(v); v = dpp_fmax_step<0x118>(v);
  v = dpp_fmax_step<0x142>(v); v = dpp_fmax_step<0x143>(v);
  return __int_as_float(__builtin_amdgcn_readlane(__float_as_int(v), 63));
}
template <int CTRL>
__device__ __forceinline__ float dpp_fadd_step(float v) {
  int t = __builtin_amdgcn_update_dpp(0, __float_as_int(v), CTRL, 0xf, 0xf, true);
  return v + __int_as_float(t);
}
__device__ __forceinline__ float wave_sum_all(float v) {
  v = dpp_fadd_step<0x111>(v); v = dpp_fadd_step<0x112>(v);
  v = dpp_fadd_step<0x114>(v); v = dpp_fadd_step<0x118>(v);
  v = dpp_fadd_step<0x142>(v); v = dpp_fadd_step<0x143>(v);
  return __int_as_float(__builtin_amdgcn_readlane(__float_as_int(v), 63));
}
__device__ __forceinline__ unsigned short f2bf(float v) {   // round-half-up (positive)
  return (unsigned short)((__float_as_uint(v) + 0x8000u) >> 16);
}
__device__ __forceinline__ float bf2f(unsigned short u) {
  return __uint_as_float(((unsigned)u) << 16);
}

// ===== lens: len[b] = round(sum(mask[b,:])) =====
__global__ __launch_bounds__(256) void crf_lens(
    const float* __restrict__ mask, int* __restrict__ lens, int B)
{
  const int b = blockIdx.x * 4 + (threadIdx.x >> 6);
  if (b >= B) return;
  const int l = threadIdx.x & 63;
  const float4* mb = (const float4*)(mask + (size_t)b * S_LEN);
  float s = 0.f;
#pragma unroll
  for (int i = 0; i < 4; ++i) { float4 q = mb[l + 64 * i]; s += q.x + q.y + q.z + q.w; }
  s = wave_sum_all(s);
  if (l == 0) lens[b] = max(1, min(S_LEN, (int)(s + 0.5f)));
}

// ===== ptab: per-lane MFMA B-fragment table + exp(trans[:,EOS]) =====
__global__ __launch_bounds__(256) void crf_ptab(
    const float* __restrict__ trans, short8* __restrict__ pfrag,
    float* __restrict__ tvf)
{
  const int tid = threadIdx.x;
  for (int e = tid; e < 1024; e += 256) {
    int lane = e & 63, n = (e >> 6) & 3, kc = (e >> 8) & 1, dir = e >> 9;
    int g = lane >> 4, c = lane & 15, col = 4 * c + n;
    short8 f;
#pragma unroll
    for (int j = 0; j < 8; ++j) {
      int k = kc * 32 + g * 8 + j;
      float tv = dir ? trans[col * 64 + k] : trans[k * 64 + col];
      f[j] = (short)f2bf(__expf(tv));
    }
    pfrag[e] = f;
  }
  if (tid < 64) tvf[tid] = __expf(trans[tid * 64 + EOS_TAG]);
}

// ===== MFMA chunk kernel (exact R10 body; geometry CH=32) =====
// wave w: dir=w&1, idx=w>>1, b=idx/WPB, half=idx%WPB. Row r <-> chunk
// kg=half*16+r. State tiling: tile n, lane-col c <-> state 4c+n. A k-slot
// (kc,g,j) <-> state 32kc+8g+j. LDS bf16 word (row*64+state) ^ swizzle.
// fwd: V <- (V x P) .* E_t. bwd: V <- (V .* E_t) x P^T (A-side multiply).
// NOTES: (256,3) = proven no-spill launch bound. R11-R15 bwd w-state
// restructure + epi_save regressed 75.6->120us chunks (persistent 60-70MB
// scratch-like writes, cause never isolated) — reverted wholesale to the
// R10-measured body. Only CH/NCH/WPB changed (startup amortization).
__global__ __launch_bounds__(256, 3) void crf_chunk_mfma(
    const float* __restrict__ em, const float* __restrict__ trans,
    const int* __restrict__ lens, const short8* __restrict__ pfrag,
    unsigned short* __restrict__ Vf, unsigned short* __restrict__ Vb,
    float* __restrict__ sf, float* __restrict__ sb,
    float* __restrict__ m0a, int B)
{
  __shared__ unsigned short smem[4][16 * 64];
  const int wv = threadIdx.x >> 6;
  const int l  = threadIdx.x & 63;
  const int w  = blockIdx.x * 4 + wv;
  const int nwaves = 2 * B * WPB;
  if (w >= nwaves) return;
  const int dir  = w & 1;
  const int idx  = w >> 1;
  const int b    = idx / WPB;
  const int half = idx % WPB;
  unsigned short* smw = smem[wv];
  const float* embase = em + (size_t)b * S_LEN * 64;
  const int g = l >> 4, c = l & 15;

  const int len = lens[b];

  // ---- alpha0 (fwd half==0 only) ----
  float v_row0 = 1.0f;
  if (dir == 0 && half == 0) {
    float a0 = trans[BOS_TAG * 64 + l] + embase[l];
    float m0 = wave_fmax_all(a0);
    v_row0 = __expf(a0 - m0);
    if (l == 0) m0a[b] = m0;
  }

  // ---- per-row step counts; pre-save empty rows; find the partial row ----
  unsigned short* Vout = dir ? Vb : Vf;
  float* sout = dir ? sb : sf;
  int fstep[16];
  int ps = -1, pr = -1;
#pragma unroll
  for (int r = 0; r < 16; ++r) {
    int kg = half * 16 + r;
    int tend = min((kg + 1) * CH, len - 1);
    fstep[r] = tend - (kg * CH + 1);
    if (fstep[r] < 0) {
      Vout[((size_t)b * NCH + kg) * 64 + l] = 0x3F80; // bf16 1.0
      if (l == 0) sout[b * NCH + kg] = 0.f;
    }
    if (fstep[r] >= 0 && fstep[r] < CH - 1) { ps = fstep[r]; pr = r; }
  }

  if (half * 16 * CH + 1 > len - 1) return; // fully-empty wave

  // ---- B fragments: 8 coalesced 16B loads from pfrag ----
  short8 Bf[2][4];
  {
    const short8* pf = pfrag + dir * 512;
#pragma unroll
    for (int kc = 0; kc < 2; ++kc)
#pragma unroll
      for (int n = 0; n < 4; ++n)
        Bf[kc][n] = pf[(kc * 4 + n) * 64 + l];
  }

  // ---- init V rows (swizzled LDS [16][64] bf16) ----
#pragma unroll
  for (int r = 0; r < 16; ++r) {
    float v = (dir == 0 && half == 0 && r == 0) ? v_row0 : 1.0f;
    smw[(r * 64 + l) ^ ((r & 7) << 3)] = f2bf(v);
  }

  const int byteA0 = (c * 128 + g * 16) ^ ((c & 7) << 4);
  const int byteA1 = (c * 128 + 64 + g * 16) ^ ((c & 7) << 4);
  int sigma = 0;

  auto renorm16 = [&](float* d) {
    float m = d[0];
#pragma unroll
    for (int i = 1; i < 16; ++i) m = fmaxf(m, d[i]);
    m = wave_fmax_all(m);
    int e = ((__float_as_int(m) >> 23) & 0xff) - 127;
    float s = __int_as_float((127 - e) << 23);
#pragma unroll
    for (int i = 0; i < 16; ++i) d[i] *= s;
    sigma += e;
  };
  auto save_row = [&](int r) {
    unsigned short v = smw[(r * 64 + l) ^ ((r & 7) << 3)];
    int kg = half * 16 + r;
    Vout[((size_t)b * NCH + kg) * 64 + l] = v;
    if (l == 0) sout[b * NCH + kg] = (float)sigma;
  };
  auto write_d = [&](const float* d) {
#pragma unroll
    for (int reg = 0; reg < 4; ++reg) {
      int row = g * 4 + reg;
      ushort4v wq;
#pragma unroll
      for (int n = 0; n < 4; ++n) wq[n] = f2bf(d[reg * 4 + n]);
      *reinterpret_cast<ushort4v*>(
          (char*)smw + ((row * 128 + c * 8) ^ ((row & 7) << 4))) = wq;
    }
  };

  if (dir == 0) {
    int tb0[4];
#pragma unroll
    for (int reg = 0; reg < 4; ++reg) tb0[reg] = (half * 16 + g * 4 + reg) * CH + 1;

    auto loadF = [&](float4* q, int tl) {
#pragma unroll
      for (int reg = 0; reg < 4; ++reg) {
        int tr = min(tb0[reg] + tl, S_LEN - 1);
        q[reg] = *reinterpret_cast<const float4*>(embase + (size_t)tr * 64 + 4 * c);
      }
    };
    auto bodyF = [&](const float4* q, int tl, bool rn) {
      f32x4 acc[4];
      {
        short8 a0 = *reinterpret_cast<const short8*>((const char*)smw + byteA0);
        short8 a1 = *reinterpret_cast<const short8*>((const char*)smw + byteA1);
#pragma unroll
        for (int n = 0; n < 4; ++n) {
          f32x4 z = {0.f, 0.f, 0.f, 0.f};
          z = __builtin_amdgcn_mfma_f32_16x16x32_bf16(a0, Bf[0][n], z, 0, 0, 0);
          acc[n] = __builtin_amdgcn_mfma_f32_16x16x32_bf16(a1, Bf[1][n], z, 0, 0, 0);
        }
      }
      float d[16];
#pragma unroll
      for (int reg = 0; reg < 4; ++reg) {
        d[reg * 4 + 0] = acc[0][reg] * __expf(q[reg].x);
        d[reg * 4 + 1] = acc[1][reg] * __expf(q[reg].y);
        d[reg * 4 + 2] = acc[2][reg] * __expf(q[reg].z);
        d[reg * 4 + 3] = acc[3][reg] * __expf(q[reg].w);
      }
      if (rn) renorm16(d);
      write_d(d);
      if (tl == ps) save_row(pr);
    };

    float4 p0[4], p1[4], p2[4], p3[4];
    loadF(p0, 0); loadF(p1, 1); loadF(p2, 2); loadF(p3, 3);
#pragma unroll 1
    for (int t4 = 0; t4 < CH; t4 += 4) {
      bodyF(p0, t4 + 0, false); loadF(p0, t4 + 4);
      bodyF(p1, t4 + 1, false); loadF(p1, t4 + 5);
      bodyF(p2, t4 + 2, false); loadF(p2, t4 + 6);
      bodyF(p3, t4 + 3, true);  loadF(p3, t4 + 7);
    }
#pragma unroll
    for (int r = 0; r < 16; ++r)
      if (fstep[r] == CH - 1) save_row(r);
  } else {
    // ---- bwd: A rows are chains rc = c; E applied on A side ----
    const int tendl = min((half * 16 + c + 1) * CH, len - 1);

    auto loadB = [&](float4* q, int tl) {
      int tr = max(tendl - tl, 0);
      const float* rowp = embase + (size_t)tr * 64;
      q[0] = *reinterpret_cast<const float4*>(rowp + 8 * g);
      q[1] = *reinterpret_cast<const float4*>(rowp + 8 * g + 4);
      q[2] = *reinterpret_cast<const float4*>(rowp + 32 + 8 * g);
      q[3] = *reinterpret_cast<const float4*>(rowp + 32 + 8 * g + 4);
    };
    auto bodyB = [&](const float4* q, int tl, bool rn) {
      short8 ar0 = *reinterpret_cast<const short8*>((const char*)smw + byteA0);
      short8 ar1 = *reinterpret_cast<const short8*>((const char*)smw + byteA1);
      short8 a0, a1;
#pragma unroll
      for (int j = 0; j < 4; ++j) {
        a0[j]     = (short)f2bf(bf2f((unsigned short)ar0[j])     * __expf(((const float*)&q[0])[j]));
        a0[4 + j] = (short)f2bf(bf2f((unsigned short)ar0[4 + j]) * __expf(((const float*)&q[1])[j]));
        a1[j]     = (short)f2bf(bf2f((unsigned short)ar1[j])     * __expf(((const float*)&q[2])[j]));
        a1[4 + j] = (short)f2bf(bf2f((unsigned short)ar1[4 + j]) * __expf(((const float*)&q[3])[j]));
      }
      f32x4 acc[4];
#pragma unroll
      for (int n = 0; n < 4; ++n) {
        f32x4 z = {0.f, 0.f, 0.f, 0.f};
        z = __builtin_amdgcn_mfma_f32_16x16x32_bf16(a0, Bf[0][n], z, 0, 0, 0);
        acc[n] = __builtin_amdgcn_mfma_f32_16x16x32_bf16(a1, Bf[1][n], z, 0, 0, 0);
      }
      float d[16];
#pragma unroll
      for (int reg = 0; reg < 4; ++reg)
#pragma unroll
        for (int n = 0; n < 4; ++n) d[reg * 4 + n] = acc[n][reg];
      if (rn) renorm16(d);
      write_d(d);
      if (tl == ps) save_row(pr);
    };

    float4 p0[4], p1[4], p2[4], p3[4];
    loadB(p0, 0); loadB(p1, 1); loadB(p2, 2); loadB(p3, 3);
#pragma unroll 1
    for (int t4 = 0; t4 < CH; t4 += 4) {
      bodyB(p0, t4 + 0, false); loadB(p0, t4 + 4);
      bodyB(p1, t4 + 1, false); loadB(p1, t4 + 5);
      bodyB(p2, t4 + 2, false); loadB(p2, t4 + 6);
      bodyB(p3, t4 + 3, true);  loadB(p3, t4 + 7);
    }
#pragma unroll
    for (int r = 0; r < 16; ++r)
      if (fstep[r] == CH - 1) save_row(r);
  }
}

// ===== combine: one wave per (b,k) term; includes gold-score slice =====
__global__ __launch_bounds__(256) void crf_combine(
    const float* __restrict__ em, const int* __restrict__ tags,
    const float* __restrict__ trans, const int* __restrict__ lens,
    const unsigned short* __restrict__ Vf, const unsigned short* __restrict__ Vb,
    const float* __restrict__ sf, const float* __restrict__ sb,
    const float* __restrict__ m0a, const float* __restrict__ tvf,
    float* __restrict__ term, int B)
{
  const int item = blockIdx.x * 4 + (threadIdx.x >> 6);
  if (item >= B * NCH) return;
  const int b = item / NCH, k = item - b * NCH;
  const int l = threadIdx.x & 63;
  const int len = lens[b];
  const int kb = (len >= 2) ? (len - 2) / CH : 0;

  const int* tb = tags + (size_t)b * S_LEN;
  const float* emb = em + (size_t)b * S_LEN * 64;

  float t = 0.f;
  // ---- gold score slice (negated): steps t0 = k*CH+1 .. min((k+1)CH, len-1)
  {
    float sc = 0.f;
    int t0 = k * CH + 1 + l;
    if (l < CH && t0 <= len - 1) {
      int cur = tb[t0], prev = tb[t0 - 1];
      sc = emb[(size_t)t0 * 64 + cur] + trans[prev * 64 + cur];
    }
    if (k == 0) {
      if (l == 32) sc += trans[BOS_TAG * 64 + tb[0]] + emb[tb[0]];
      if (l == 33) sc += trans[tb[len - 1] * 64 + EOS_TAG];
    }
    t -= wave_sum_all(sc);
  }

  const unsigned short* vf = Vf + ((size_t)b * NCH + k) * 64;
  if (k == 0) {
    float v0 = bf2f(vf[l]);
    if (kb == 0) {
      t += m0a[b] + LN2F * sf[b * NCH] + __logf(wave_sum_all(v0 * tvf[l]));
    } else {
      t += m0a[b] + LN2F * (sf[b * NCH] + sb[b * NCH + 1])
         + __logf(wave_sum_all(v0 * bf2f(Vb[((size_t)b * NCH + 1) * 64 + l])));
    }
  } else if (k < kb) {
    float vk = bf2f(vf[l]);
    t += LN2F * sb[b * NCH + k + 1]
       + __logf(wave_sum_all(vk * bf2f(Vb[((size_t)b * NCH + k + 1) * 64 + l])))
       - __logf(wave_sum_all(vk));
  } else if (k == kb) {
    float vk = bf2f(vf[l]);
    t += __logf(wave_sum_all(vk * tvf[l])) - __logf(wave_sum_all(vk));
  }

  if (l == 0) term[item] = t;
}

// ===== final: sum all terms -> out[0] =====
__global__ __launch_bounds__(1024) void crf_final(
    const float* __restrict__ term, float* __restrict__ out, int n)
{
  __shared__ float red[16];
  float s = 0.f;
  for (int i = threadIdx.x; i < n; i += 1024) s += term[i];
  s = wave_sum_all(s);
  const int wid = threadIdx.x >> 6;
  if ((threadIdx.x & 63) == 0) red[wid] = s;
  __syncthreads();
  if (threadIdx.x == 0) {
    float tot = 0.f;
#pragma unroll
    for (int i = 0; i < 16; ++i) tot += red[i];
    out[0] = tot;
  }
}

// ===== fallback: monolithic per-batch forward (VALU, linear space) =====
__global__ __launch_bounds__(64) void crf_mono(
    const float* __restrict__ em, const int* __restrict__ tags,
    const float* __restrict__ mask, const float* __restrict__ trans,
    float* __restrict__ partial)
{
  const int b = blockIdx.x;
  const int l = threadIdx.x;
  const float* emb = em + (size_t)b * S_LEN * 64;
  const float* mb = mask + (size_t)b * S_LEN;
  float lenf = 0.f;
  for (int t = l; t < S_LEN; t += 64) lenf += mb[t];
  lenf = wave_sum_all(lenf);
  const int len = max(1, min(S_LEN, (int)(lenf + 0.5f)));

  float p[64];
#pragma unroll
  for (int i = 0; i < 64; ++i) p[i] = __expf(trans[i * 64 + l]) * 0.015625f;

  const int* tb = tags + (size_t)b * S_LEN;
  float sc = 0.f;
  for (int tt = 1 + l; tt <= len - 1; tt += 64)
    sc += emb[(size_t)tt * 64 + tb[tt]] + trans[tb[tt - 1] * 64 + tb[tt]];
  sc = wave_sum_all(sc);
  sc += trans[BOS_TAG * 64 + tb[0]] + emb[tb[0]] + trans[tb[len - 1] * 64 + EOS_TAG];

  float a0 = trans[BOS_TAG * 64 + l] + emb[l];
  float m0 = wave_fmax_all(a0);
  float v = __expf(a0 - m0);
  int sigma = 0;
  for (int t = 1; t <= len - 1; ++t) {
    float E = __expf(emb[(size_t)t * 64 + l]);
    int xi = __float_as_int(v);
    float s0 = 0.f, s1 = 0.f, s2 = 0.f, s3 = 0.f;
#pragma unroll
    for (int i = 0; i < 64; i += 4) {
      s0 = fmaf(__int_as_float(__builtin_amdgcn_readlane(xi, i + 0)), p[i + 0], s0);
      s1 = fmaf(__int_as_float(__builtin_amdgcn_readlane(xi, i + 1)), p[i + 1], s1);
      s2 = fmaf(__int_as_float(__builtin_amdgcn_readlane(xi, i + 2)), p[i + 2], s2);
      s3 = fmaf(__int_as_float(__builtin_amdgcn_readlane(xi, i + 3)), p[i + 3], s3);
    }
    v = ((s0 + s1) + (s2 + s3)) * E;
    float m = wave_fmax_all(v);
    int e = ((__float_as_int(m) >> 23) & 0xff) - 127;
    sigma += e + 6;
    v *= __int_as_float((127 - e) << 23);
  }
  float tvec = __expf(trans[l * 64 + EOS_TAG]);
  float lp = m0 + LN2F * (float)sigma + __logf(wave_sum_all(v * tvec));
  if (l == 0) partial[b] = lp - sc;
}

extern "C" void kernel_launch(void* const* d_in, const int* in_sizes, int n_in,
                              void* d_out, int out_size, void* d_ws, size_t ws_size,
                              hipStream_t stream) {
  const float* em = (const float*)d_in[0];
  const int* tags = (const int*)d_in[1];
  const float* mask = (const float*)d_in[2];
  const float* trans = (const float*)d_in[3];
  float* out = (float*)d_out;

  const int B = in_sizes[1] / S_LEN;

  const size_t nSig = (size_t)B * NCH;
  const size_t nV   = (size_t)B * NCH * 64;
  const size_t need = 16384 + 64 * sizeof(float)
                    + (3 * nSig + (size_t)B) * sizeof(float)
                    + (size_t)B * sizeof(int)
                    + 2 * nV * sizeof(unsigned short);

  if (ws_size >= need) {
    short8* pfrag = (short8*)d_ws;
    float* tvf  = (float*)((char*)d_ws + 16384);
    float* sf   = tvf + 64;
    float* sb   = sf + nSig;
    float* m0a  = sb + nSig;
    float* term = m0a + B;
    int*   lens = (int*)(term + nSig);
    unsigned short* Vf = (unsigned short*)(lens + B);
    unsigned short* Vb = Vf + nV;

    crf_lens<<<(B + 3) / 4, 256, 0, stream>>>(mask, lens, B);
    crf_ptab<<<1, 256, 0, stream>>>(trans, pfrag, tvf);
    const int nwaves = 2 * B * WPB;
    crf_chunk_mfma<<<(nwaves + 3) / 4, 256, 0, stream>>>(
        em, trans, lens, pfrag, Vf, Vb, sf, sb, m0a, B);
    crf_combine<<<(B * NCH + 3) / 4, 256, 0, stream>>>(
        em, tags, trans, lens, Vf, Vb, sf, sb, m0a, tvf, term, B);
    crf_final<<<1, 1024, 0, stream>>>(term, out, B * NCH);
  } else {
    float* partial = (float*)d_ws;
    crf_mono<<<B, 64, 0, stream>>>(em, tags, mask, trans, partial);
    crf_final<<<1, 1024, 0, stream>>>(partial, out, B);
  }
}

// Round 17
// 66.062 us; speedup vs baseline: 1.8510x; 1.1160x over previous
//
#include <hip/hip_runtime.h>
#include <math.h>

#define BOS_TAG 62
#define EOS_TAG 63
#define S_LEN   1024
#define NCH     16
#define CH      64          // S_LEN / NCH
#define WPB     1           // NCH/16 fwd waves per batch (same for bwd)
#define LN2F    0.69314718055994530942f

typedef short  short8 __attribute__((ext_vector_type(8)));
typedef unsigned short ushort4v __attribute__((ext_vector_type(4)));
typedef float  f32x4  __attribute__((ext_vector_type(4)));

template <int CTRL>
__device__ __forceinline__ int dpp_mov(int v) {
  return __builtin_amdgcn_update_dpp(v, v, CTRL, 0xf, 0xf, false);
}
template <int CTRL>
__device__ __forceinline__ float dpp_fmax_step(float v) {
  return fmaxf(v, __int_as_float(dpp_mov<CTRL>(__float_as_int(v))));
}
__device__ __forceinline__ float wave_fmax_all(float v) {
  v = dpp_fmax_step<0x111>(v); v = dpp_fmax_step<0x112>(v);
  v = dpp_fmax_step<0x114>(v); v = dpp_fmax_step<0x118>(v);
  v = dpp_fmax_step<0x142>(v); v = dpp_fmax_step<0x143>(v);
  return __int_as_float(__builtin_amdgcn_readlane(__float_as_int(v), 63));
}
template <int CTRL>
__device__ __forceinline__ float dpp_fadd_step(float v) {
  int t = __builtin_amdgcn_update_dpp(0, __float_as_int(v), CTRL, 0xf, 0xf, true);
  return v + __int_as_float(t);
}
__device__ __forceinline__ float wave_sum_all(float v) {
  v = dpp_fadd_step<0x111>(v); v = dpp_fadd_step<0x112>(v);
  v = dpp_fadd_step<0x114>(v); v = dpp_fadd_step<0x118>(v);
  v = dpp_fadd_step<0x142>(v); v = dpp_fadd_step<0x143>(v);
  return __int_as_float(__builtin_amdgcn_readlane(__float_as_int(v), 63));
}
__device__ __forceinline__ unsigned short f2bf(float v) {   // round-half-up (positive)
  return (unsigned short)((__float_as_uint(v) + 0x8000u) >> 16);
}
__device__ __forceinline__ float bf2f(unsigned short u) {
  return __uint_as_float(((unsigned)u) << 16);
}

// ===== lens: len[b] = round(sum(mask[b,:])) =====
__global__ __launch_bounds__(256) void crf_lens(
    const float* __restrict__ mask, int* __restrict__ lens, int B)
{
  const int b = blockIdx.x * 4 + (threadIdx.x >> 6);
  if (b >= B) return;
  const int l = threadIdx.x & 63;
  const float4* mb = (const float4*)(mask + (size_t)b * S_LEN);
  float s = 0.f;
#pragma unroll
  for (int i = 0; i < 4; ++i) { float4 q = mb[l + 64 * i]; s += q.x + q.y + q.z + q.w; }
  s = wave_sum_all(s);
  if (l == 0) lens[b] = max(1, min(S_LEN, (int)(s + 0.5f)));
}

// ===== ptab: per-lane MFMA B-fragment table + exp(trans[:,EOS]) =====
__global__ __launch_bounds__(256) void crf_ptab(
    const float* __restrict__ trans, short8* __restrict__ pfrag,
    float* __restrict__ tvf)
{
  const int tid = threadIdx.x;
  for (int e = tid; e < 1024; e += 256) {
    int lane = e & 63, n = (e >> 6) & 3, kc = (e >> 8) & 1, dir = e >> 9;
    int g = lane >> 4, c = lane & 15, col = 4 * c + n;
    short8 f;
#pragma unroll
    for (int j = 0; j < 8; ++j) {
      int k = kc * 32 + g * 8 + j;
      float tv = dir ? trans[col * 64 + k] : trans[k * 64 + col];
      f[j] = (short)f2bf(__expf(tv));
    }
    pfrag[e] = f;
  }
  if (tid < 64) tvf[tid] = __expf(trans[tid * 64 + EOS_TAG]);
}

// ===== MFMA chunk kernel (R10/R16-proven body; geometry CH=64) =====
// wave w: dir=w&1, idx=w>>1, b=idx/WPB, half=idx%WPB. Row r <-> chunk
// kg=half*16+r. State tiling: tile n, lane-col c <-> state 4c+n. A k-slot
// (kc,g,j) <-> state 32kc+8g+j. LDS bf16 word (row*64+state) ^ swizzle.
// fwd: V <- (V x P) .* E_t. bwd: V <- (V .* E_t) x P^T (A-side multiply).
// NOTES: (256,3) = proven no-spill launch bound. Geometry gradient measured:
// CH=16 -> 75.6us chunk, CH=32 -> ~60us (R16, total 73.7). Body must stay
// EXACTLY the R10 form (R11-R15 bwd restructure regressed 1.6x, never
// isolated -> wholesale revert was the fix).
__global__ __launch_bounds__(256, 3) void crf_chunk_mfma(
    const float* __restrict__ em, const float* __restrict__ trans,
    const int* __restrict__ lens, const short8* __restrict__ pfrag,
    unsigned short* __restrict__ Vf, unsigned short* __restrict__ Vb,
    float* __restrict__ sf, float* __restrict__ sb,
    float* __restrict__ m0a, int B)
{
  __shared__ unsigned short smem[4][16 * 64];
  const int wv = threadIdx.x >> 6;
  const int l  = threadIdx.x & 63;
  const int w  = blockIdx.x * 4 + wv;
  const int nwaves = 2 * B * WPB;
  if (w >= nwaves) return;
  const int dir  = w & 1;
  const int idx  = w >> 1;
  const int b    = idx / WPB;
  const int half = idx % WPB;
  unsigned short* smw = smem[wv];
  const float* embase = em + (size_t)b * S_LEN * 64;
  const int g = l >> 4, c = l & 15;

  const int len = lens[b];

  // ---- alpha0 (fwd half==0 only) ----
  float v_row0 = 1.0f;
  if (dir == 0 && half == 0) {
    float a0 = trans[BOS_TAG * 64 + l] + embase[l];
    float m0 = wave_fmax_all(a0);
    v_row0 = __expf(a0 - m0);
    if (l == 0) m0a[b] = m0;
  }

  // ---- per-row step counts; pre-save empty rows; find the partial row ----
  unsigned short* Vout = dir ? Vb : Vf;
  float* sout = dir ? sb : sf;
  int fstep[16];
  int ps = -1, pr = -1;
#pragma unroll
  for (int r = 0; r < 16; ++r) {
    int kg = half * 16 + r;
    int tend = min((kg + 1) * CH, len - 1);
    fstep[r] = tend - (kg * CH + 1);
    if (fstep[r] < 0) {
      Vout[((size_t)b * NCH + kg) * 64 + l] = 0x3F80; // bf16 1.0
      if (l == 0) sout[b * NCH + kg] = 0.f;
    }
    if (fstep[r] >= 0 && fstep[r] < CH - 1) { ps = fstep[r]; pr = r; }
  }

  if (half * 16 * CH + 1 > len - 1) return; // fully-empty wave

  // ---- B fragments: 8 coalesced 16B loads from pfrag ----
  short8 Bf[2][4];
  {
    const short8* pf = pfrag + dir * 512;
#pragma unroll
    for (int kc = 0; kc < 2; ++kc)
#pragma unroll
      for (int n = 0; n < 4; ++n)
        Bf[kc][n] = pf[(kc * 4 + n) * 64 + l];
  }

  // ---- init V rows (swizzled LDS [16][64] bf16) ----
#pragma unroll
  for (int r = 0; r < 16; ++r) {
    float v = (dir == 0 && half == 0 && r == 0) ? v_row0 : 1.0f;
    smw[(r * 64 + l) ^ ((r & 7) << 3)] = f2bf(v);
  }

  const int byteA0 = (c * 128 + g * 16) ^ ((c & 7) << 4);
  const int byteA1 = (c * 128 + 64 + g * 16) ^ ((c & 7) << 4);
  int sigma = 0;

  auto renorm16 = [&](float* d) {
    float m = d[0];
#pragma unroll
    for (int i = 1; i < 16; ++i) m = fmaxf(m, d[i]);
    m = wave_fmax_all(m);
    int e = ((__float_as_int(m) >> 23) & 0xff) - 127;
    float s = __int_as_float((127 - e) << 23);
#pragma unroll
    for (int i = 0; i < 16; ++i) d[i] *= s;
    sigma += e;
  };
  auto save_row = [&](int r) {
    unsigned short v = smw[(r * 64 + l) ^ ((r & 7) << 3)];
    int kg = half * 16 + r;
    Vout[((size_t)b * NCH + kg) * 64 + l] = v;
    if (l == 0) sout[b * NCH + kg] = (float)sigma;
  };
  auto write_d = [&](const float* d) {
#pragma unroll
    for (int reg = 0; reg < 4; ++reg) {
      int row = g * 4 + reg;
      ushort4v wq;
#pragma unroll
      for (int n = 0; n < 4; ++n) wq[n] = f2bf(d[reg * 4 + n]);
      *reinterpret_cast<ushort4v*>(
          (char*)smw + ((row * 128 + c * 8) ^ ((row & 7) << 4))) = wq;
    }
  };

  if (dir == 0) {
    int tb0[4];
#pragma unroll
    for (int reg = 0; reg < 4; ++reg) tb0[reg] = (half * 16 + g * 4 + reg) * CH + 1;

    auto loadF = [&](float4* q, int tl) {
#pragma unroll
      for (int reg = 0; reg < 4; ++reg) {
        int tr = min(tb0[reg] + tl, S_LEN - 1);
        q[reg] = *reinterpret_cast<const float4*>(embase + (size_t)tr * 64 + 4 * c);
      }
    };
    auto bodyF = [&](const float4* q, int tl, bool rn) {
      f32x4 acc[4];
      {
        short8 a0 = *reinterpret_cast<const short8*>((const char*)smw + byteA0);
        short8 a1 = *reinterpret_cast<const short8*>((const char*)smw + byteA1);
#pragma unroll
        for (int n = 0; n < 4; ++n) {
          f32x4 z = {0.f, 0.f, 0.f, 0.f};
          z = __builtin_amdgcn_mfma_f32_16x16x32_bf16(a0, Bf[0][n], z, 0, 0, 0);
          acc[n] = __builtin_amdgcn_mfma_f32_16x16x32_bf16(a1, Bf[1][n], z, 0, 0, 0);
        }
      }
      float d[16];
#pragma unroll
      for (int reg = 0; reg < 4; ++reg) {
        d[reg * 4 + 0] = acc[0][reg] * __expf(q[reg].x);
        d[reg * 4 + 1] = acc[1][reg] * __expf(q[reg].y);
        d[reg * 4 + 2] = acc[2][reg] * __expf(q[reg].z);
        d[reg * 4 + 3] = acc[3][reg] * __expf(q[reg].w);
      }
      if (rn) renorm16(d);
      write_d(d);
      if (tl == ps) save_row(pr);
    };

    float4 p0[4], p1[4], p2[4], p3[4];
    loadF(p0, 0); loadF(p1, 1); loadF(p2, 2); loadF(p3, 3);
#pragma unroll 1
    for (int t4 = 0; t4 < CH; t4 += 4) {
      bodyF(p0, t4 + 0, false); loadF(p0, t4 + 4);
      bodyF(p1, t4 + 1, false); loadF(p1, t4 + 5);
      bodyF(p2, t4 + 2, false); loadF(p2, t4 + 6);
      bodyF(p3, t4 + 3, true);  loadF(p3, t4 + 7);
    }
#pragma unroll
    for (int r = 0; r < 16; ++r)
      if (fstep[r] == CH - 1) save_row(r);
  } else {
    // ---- bwd: A rows are chains rc = c; E applied on A side ----
    const int tendl = min((half * 16 + c + 1) * CH, len - 1);

    auto loadB = [&](float4* q, int tl) {
      int tr = max(tendl - tl, 0);
      const float* rowp = embase + (size_t)tr * 64;
      q[0] = *reinterpret_cast<const float4*>(rowp + 8 * g);
      q[1] = *reinterpret_cast<const float4*>(rowp + 8 * g + 4);
      q[2] = *reinterpret_cast<const float4*>(rowp + 32 + 8 * g);
      q[3] = *reinterpret_cast<const float4*>(rowp + 32 + 8 * g + 4);
    };
    auto bodyB = [&](const float4* q, int tl, bool rn) {
      short8 ar0 = *reinterpret_cast<const short8*>((const char*)smw + byteA0);
      short8 ar1 = *reinterpret_cast<const short8*>((const char*)smw + byteA1);
      short8 a0, a1;
#pragma unroll
      for (int j = 0; j < 4; ++j) {
        a0[j]     = (short)f2bf(bf2f((unsigned short)ar0[j])     * __expf(((const float*)&q[0])[j]));
        a0[4 + j] = (short)f2bf(bf2f((unsigned short)ar0[4 + j]) * __expf(((const float*)&q[1])[j]));
        a1[j]     = (short)f2bf(bf2f((unsigned short)ar1[j])     * __expf(((const float*)&q[2])[j]));
        a1[4 + j] = (short)f2bf(bf2f((unsigned short)ar1[4 + j]) * __expf(((const float*)&q[3])[j]));
      }
      f32x4 acc[4];
#pragma unroll
      for (int n = 0; n < 4; ++n) {
        f32x4 z = {0.f, 0.f, 0.f, 0.f};
        z = __builtin_amdgcn_mfma_f32_16x16x32_bf16(a0, Bf[0][n], z, 0, 0, 0);
        acc[n] = __builtin_amdgcn_mfma_f32_16x16x32_bf16(a1, Bf[1][n], z, 0, 0, 0);
      }
      float d[16];
#pragma unroll
      for (int reg = 0; reg < 4; ++reg)
#pragma unroll
        for (int n = 0; n < 4; ++n) d[reg * 4 + n] = acc[n][reg];
      if (rn) renorm16(d);
      write_d(d);
      if (tl == ps) save_row(pr);
    };

    float4 p0[4], p1[4], p2[4], p3[4];
    loadB(p0, 0); loadB(p1, 1); loadB(p2, 2); loadB(p3, 3);
#pragma unroll 1
    for (int t4 = 0; t4 < CH; t4 += 4) {
      bodyB(p0, t4 + 0, false); loadB(p0, t4 + 4);
      bodyB(p1, t4 + 1, false); loadB(p1, t4 + 5);
      bodyB(p2, t4 + 2, false); loadB(p2, t4 + 6);
      bodyB(p3, t4 + 3, true);  loadB(p3, t4 + 7);
    }
#pragma unroll
    for (int r = 0; r < 16; ++r)
      if (fstep[r] == CH - 1) save_row(r);
  }
}

// ===== combine: one wave per (b,k) term; includes gold-score slice =====
__global__ __launch_bounds__(256) void crf_combine(
    const float* __restrict__ em, const int* __restrict__ tags,
    const float* __restrict__ trans, const int* __restrict__ lens,
    const unsigned short* __restrict__ Vf, const unsigned short* __restrict__ Vb,
    const float* __restrict__ sf, const float* __restrict__ sb,
    const float* __restrict__ m0a, const float* __restrict__ tvf,
    float* __restrict__ term, int B)
{
  const int item = blockIdx.x * 4 + (threadIdx.x >> 6);
  if (item >= B * NCH) return;
  const int b = item / NCH, k = item - b * NCH;
  const int l = threadIdx.x & 63;
  const int len = lens[b];
  const int kb = (len >= 2) ? (len - 2) / CH : 0;

  const int* tb = tags + (size_t)b * S_LEN;
  const float* emb = em + (size_t)b * S_LEN * 64;

  float t = 0.f;
  // ---- gold score slice (negated): steps t0 = k*CH+1 .. min((k+1)CH, len-1)
  {
    float sc = 0.f;
    int t0 = k * CH + 1 + l;
    if (l < CH && t0 <= len - 1) {
      int cur = tb[t0], prev = tb[t0 - 1];
      sc = emb[(size_t)t0 * 64 + cur] + trans[prev * 64 + cur];
    }
    if (k == 0) {
      if (l == 32) sc += trans[BOS_TAG * 64 + tb[0]] + emb[tb[0]];
      if (l == 33) sc += trans[tb[len - 1] * 64 + EOS_TAG];
    }
    t -= wave_sum_all(sc);
  }

  const unsigned short* vf = Vf + ((size_t)b * NCH + k) * 64;
  if (k == 0) {
    float v0 = bf2f(vf[l]);
    if (kb == 0) {
      t += m0a[b] + LN2F * sf[b * NCH] + __logf(wave_sum_all(v0 * tvf[l]));
    } else {
      t += m0a[b] + LN2F * (sf[b * NCH] + sb[b * NCH + 1])
         + __logf(wave_sum_all(v0 * bf2f(Vb[((size_t)b * NCH + 1) * 64 + l])));
    }
  } else if (k < kb) {
    float vk = bf2f(vf[l]);
    t += LN2F * sb[b * NCH + k + 1]
       + __logf(wave_sum_all(vk * bf2f(Vb[((size_t)b * NCH + k + 1) * 64 + l])))
       - __logf(wave_sum_all(vk));
  } else if (k == kb) {
    float vk = bf2f(vf[l]);
    t += __logf(wave_sum_all(vk * tvf[l])) - __logf(wave_sum_all(vk));
  }

  if (l == 0) term[item] = t;
}

// ===== final: sum all terms -> out[0] =====
__global__ __launch_bounds__(1024) void crf_final(
    const float* __restrict__ term, float* __restrict__ out, int n)
{
  __shared__ float red[16];
  float s = 0.f;
  for (int i = threadIdx.x; i < n; i += 1024) s += term[i];
  s = wave_sum_all(s);
  const int wid = threadIdx.x >> 6;
  if ((threadIdx.x & 63) == 0) red[wid] = s;
  __syncthreads();
  if (threadIdx.x == 0) {
    float tot = 0.f;
#pragma unroll
    for (int i = 0; i < 16; ++i) tot += red[i];
    out[0] = tot;
  }
}

// ===== fallback: monolithic per-batch forward (VALU, linear space) =====
__global__ __launch_bounds__(64) void crf_mono(
    const float* __restrict__ em, const int* __restrict__ tags,
    const float* __restrict__ mask, const float* __restrict__ trans,
    float* __restrict__ partial)
{
  const int b = blockIdx.x;
  const int l = threadIdx.x;
  const float* emb = em + (size_t)b * S_LEN * 64;
  const float* mb = mask + (size_t)b * S_LEN;
  float lenf = 0.f;
  for (int t = l; t < S_LEN; t += 64) lenf += mb[t];
  lenf = wave_sum_all(lenf);
  const int len = max(1, min(S_LEN, (int)(lenf + 0.5f)));

  float p[64];
#pragma unroll
  for (int i = 0; i < 64; ++i) p[i] = __expf(trans[i * 64 + l]) * 0.015625f;

  const int* tb = tags + (size_t)b * S_LEN;
  float sc = 0.f;
  for (int tt = 1 + l; tt <= len - 1; tt += 64)
    sc += emb[(size_t)tt * 64 + tb[tt]] + trans[tb[tt - 1] * 64 + tb[tt]];
  sc = wave_sum_all(sc);
  sc += trans[BOS_TAG * 64 + tb[0]] + emb[tb[0]] + trans[tb[len - 1] * 64 + EOS_TAG];

  float a0 = trans[BOS_TAG * 64 + l] + emb[l];
  float m0 = wave_fmax_all(a0);
  float v = __expf(a0 - m0);
  int sigma = 0;
  for (int t = 1; t <= len - 1; ++t) {
    float E = __expf(emb[(size_t)t * 64 + l]);
    int xi = __float_as_int(v);
    float s0 = 0.f, s1 = 0.f, s2 = 0.f, s3 = 0.f;
#pragma unroll
    for (int i = 0; i < 64; i += 4) {
      s0 = fmaf(__int_as_float(__builtin_amdgcn_readlane(xi, i + 0)), p[i + 0], s0);
      s1 = fmaf(__int_as_float(__builtin_amdgcn_readlane(xi, i + 1)), p[i + 1], s1);
      s2 = fmaf(__int_as_float(__builtin_amdgcn_readlane(xi, i + 2)), p[i + 2], s2);
      s3 = fmaf(__int_as_float(__builtin_amdgcn_readlane(xi, i + 3)), p[i + 3], s3);
    }
    v = ((s0 + s1) + (s2 + s3)) * E;
    float m = wave_fmax_all(v);
    int e = ((__float_as_int(m) >> 23) & 0xff) - 127;
    sigma += e + 6;
    v *= __int_as_float((127 - e) << 23);
  }
  float tvec = __expf(trans[l * 64 + EOS_TAG]);
  float lp = m0 + LN2F * (float)sigma + __logf(wave_sum_all(v * tvec));
  if (l == 0) partial[b] = lp - sc;
}

extern "C" void kernel_launch(void* const* d_in, const int* in_sizes, int n_in,
                              void* d_out, int out_size, void* d_ws, size_t ws_size,
                              hipStream_t stream) {
  const float* em = (const float*)d_in[0];
  const int* tags = (const int*)d_in[1];
  const float* mask = (const float*)d_in[2];
  const float* trans = (const float*)d_in[3];
  float* out = (float*)d_out;

  const int B = in_sizes[1] / S_LEN;

  const size_t nSig = (size_t)B * NCH;
  const size_t nV   = (size_t)B * NCH * 64;
  const size_t need = 16384 + 64 * sizeof(float)
                    + (3 * nSig + (size_t)B) * sizeof(float)
                    + (size_t)B * sizeof(int)
                    + 2 * nV * sizeof(unsigned short);

  if (ws_size >= need) {
    short8* pfrag = (short8*)d_ws;
    float* tvf  = (float*)((char*)d_ws + 16384);
    float* sf   = tvf + 64;
    float* sb   = sf + nSig;
    float* m0a  = sb + nSig;
    float* term = m0a + B;
    int*   lens = (int*)(term + nSig);
    unsigned short* Vf = (unsigned short*)(lens + B);
    unsigned short* Vb = Vf + nV;

    crf_lens<<<(B + 3) / 4, 256, 0, stream>>>(mask, lens, B);
    crf_ptab<<<1, 256, 0, stream>>>(trans, pfrag, tvf);
    const int nwaves = 2 * B * WPB;
    crf_chunk_mfma<<<(nwaves + 3) / 4, 256, 0, stream>>>(
        em, trans, lens, pfrag, Vf, Vb, sf, sb, m0a, B);
    crf_combine<<<(B * NCH + 3) / 4, 256, 0, stream>>>(
        em, tags, trans, lens, Vf, Vb, sf, sb, m0a, tvf, term, B);
    crf_final<<<1, 1024, 0, stream>>>(term, out, B * NCH);
  } else {
    float* partial = (float*)d_ws;
    crf_mono<<<B, 64, 0, stream>>>(em, tags, mask, trans, partial);
    crf_final<<<1, 1024, 0, stream>>>(partial, out, B);
  }
}